// Round 7
// baseline (287.232 us; speedup 1.0000x reference)
//
#include <hip/hip_runtime.h>
#include <hip/hip_bf16.h>
#include <hip/hip_fp16.h>

#define DEVI __device__ __forceinline__

typedef _Float16 f16x8 __attribute__((ext_vector_type(8)));
typedef float f32x4 __attribute__((ext_vector_type(4)));

static constexpr int M = 32768;   // batch
static constexpr int N = 1024;    // H21
static constexpr int K = 2048;    // H1
static constexpr int BM = 256, BN = 256, BK = 64;
static constexpr int NT = K / BK;            // 32 k-tiles
static constexpr int NSTRIP = (N / BN) * 4;  // 16 partial strips

// ---- ws layout ----
static constexpr size_t WS_H    = 0;                       // f16 [M][K]      = 128 MiB
static constexpr size_t WS_W21B = 134217728;               // f16 frag-major  = 4 MiB
static constexpr size_t WS_PART = 134217728 + 4194304;     // f32 [16][M][2]  = 4 MiB

using lds_vp = __attribute__((address_space(3))) void*;
using gbl_vp = const __attribute__((address_space(1))) void*;

DEVI void async_ld16(const void* g, void* l) {
  __builtin_amdgcn_global_load_lds((gbl_vp)(size_t)g,
                                   (lds_vp)(uint32_t)(size_t)l,
                                   16, 0, 0);
}

// ---------- prep: W21 [K][N] fp32 -> w21b frag-major f16 ----------
// w21b layout: [N/16 nb][K/8 kchunk][16 col][8 k] ; lane (kq,c) of a B-frag
// reads 16B at (nb, ks*4+kq) + c -> 1KB contiguous per (n,ks) wave load.
__global__ __launch_bounds__(256)
void w21prep_kernel(const float* __restrict__ W21, _Float16* __restrict__ w21b) {
  __shared__ _Float16 lds[64][20];
  const int tid = threadIdx.x;
  const int kb = blockIdx.x;   // 0..31 -> 64 k-rows
  const int nb = blockIdx.y;   // 0..63 -> 16 cols
  const int r = tid >> 2, g = tid & 3;
  float4 v = *(const float4*)(W21 + (size_t)(kb * 64 + r) * 1024 + nb * 16 + g * 4);
  lds[r][g * 4 + 0] = (_Float16)v.x;
  lds[r][g * 4 + 1] = (_Float16)v.y;
  lds[r][g * 4 + 2] = (_Float16)v.z;
  lds[r][g * 4 + 3] = (_Float16)v.w;
  __syncthreads();
  const int chunk = tid >> 5, c = (tid >> 1) & 15, e0 = (tid & 1) * 4;
  union { _Float16 h4[4]; float2 f2; } u;
#pragma unroll
  for (int i = 0; i < 4; ++i) u.h4[i] = lds[chunk * 8 + e0 + i][c];
  *(float2*)(w21b + ((size_t)nb * 256 + kb * 8) * 128 + tid * 4) = u.f2;
}

// ---------- gemm1: h = relu(x@W1 + b1), fp32 math, f16 out ----------
__global__ __launch_bounds__(256)
void gemm1_kernel(const float* __restrict__ x, const float* __restrict__ W1,
                  const float* __restrict__ b1, _Float16* __restrict__ hout) {
  __shared__ float sx[64 * 8];
  const int tid = threadIdx.x;
  const int r0 = blockIdx.x * 64;
  if (tid < 128) {
    *(float4*)&sx[tid * 4] = *(const float4*)(x + (size_t)r0 * 8 + tid * 4);
  }
  float w1r[8][8];
#pragma unroll
  for (int j = 0; j < 8; ++j) {
    *(float4*)&w1r[j][0] = *(const float4*)(W1 + j * 2048 + tid * 8);
    *(float4*)&w1r[j][4] = *(const float4*)(W1 + j * 2048 + tid * 8 + 4);
  }
  float bb[8];
  *(float4*)&bb[0] = *(const float4*)(b1 + tid * 8);
  *(float4*)&bb[4] = *(const float4*)(b1 + tid * 8 + 4);
  __syncthreads();
  for (int r = 0; r < 64; ++r) {
    float xv[8];
    *(float4*)&xv[0] = *(float4*)&sx[r * 8];
    *(float4*)&xv[4] = *(float4*)&sx[r * 8 + 4];
    float acc[8];
#pragma unroll
    for (int c = 0; c < 8; ++c) acc[c] = bb[c];
#pragma unroll
    for (int j = 0; j < 8; ++j)
#pragma unroll
      for (int c = 0; c < 8; ++c) acc[c] = fmaf(xv[j], w1r[j][c], acc[c]);
    union { f16x8 v; float4 f4; } u;
#pragma unroll
    for (int c = 0; c < 8; ++c) u.v[c] = (_Float16)fmaxf(acc[c], 0.f);
    *(float4*)(hout + (size_t)(r0 + r) * 2048 + tid * 8) = u.f4;
  }
}

// ---------- gemm2: A-in-LDS (3x32K rotate), B-from-L2 regs, 1 barrier/tile ----------
__global__ __launch_bounds__(512, 2)
void gemm2_kernel(const _Float16* __restrict__ h, const _Float16* __restrict__ w21b,
                  const float* __restrict__ b21, const float* __restrict__ w31,
                  float* __restrict__ part) {
  __shared__ __align__(16) char smem[98304];   // 3 x 32KB A buffers / 64KB red overlay

  const int tid  = threadIdx.x;
  const int lane = tid & 63;
  const int w    = tid >> 6;      // 0..7
  const int wr   = w >> 2;        // 0..1 -> 128 rows
  const int wc   = w & 3;         // 0..3 -> 64 cols

  // block mapping: XCD = lin%8 -> nblk = lin&3 fixed per XCD pair (B slice 1MB L2-hot)
  const int lin  = blockIdx.x;    // 512 blocks
  const int nblk = lin & 3;
  const int mblk = lin >> 2;      // 0..127
  const int r0 = mblk * BM;
  const int n0 = nblk * BN;

  f32x4 acc[8][4] = {};

  // ---- A staging: 8-slot rotation swizzle; linear LDS dest, pre-swz source ----
  // dest cell = i*512+tid -> row = i*64 + (tid>>3), slot = tid&7
  // source chunk c = (slot - (row&7)) & 7 = ((tid&7) - ((tid>>3)&7)) & 7
  const int cA = ((tid & 7) - ((tid >> 3) & 7)) & 7;
  const _Float16* pA = h + (size_t)(r0 + (tid >> 3)) * K + cA * 8;

  auto stageA = [&](int t, int bufi) {
    char* d = smem + bufi * 32768 + tid * 16;
    const _Float16* g = pA + t * BK;
#pragma unroll
    for (int i = 0; i < 4; ++i)
      async_ld16(g + (size_t)i * 64 * K, d + i * 8192);
  };

  // ---- B global frag base: lane = kq*16 + c reads 16B ----
  const int nbase = nblk * 16 + wc * 4;
  const _Float16* bW = w21b + (size_t)nbase * 32768 + lane * 8;

  // ---- A frag read offsets (swizzled): frag(m,ks): row=wr*128+m*16+(lane&15),
  // chunk = ks*4+(lane>>4); slot = (chunk + row&7)&7; row&7 = lane&7 ----
  int abyteK[2];
#pragma unroll
  for (int ks = 0; ks < 2; ++ks)
    abyteK[ks] = (wr * 128 + (lane & 15)) * 128 +
                 (((ks * 4 + (lane >> 4)) + (lane & 7)) & 7) * 16;

#define SB __builtin_amdgcn_sched_barrier(0)
#define BAR __builtin_amdgcn_s_barrier()
#define LGKM(nn) asm volatile("s_waitcnt lgkmcnt(" #nn ")" ::: "memory")

  f16x8 aL[4], aH[4], bA[4][2], bB[4][2];

  // ---- prologue: A(0), B(0), A(1); vmcnt(4) retires A(0)+B(0), leaves A(1) ----
  stageA(0, 0);
#pragma unroll
  for (int n = 0; n < 4; ++n)
#pragma unroll
    for (int ks = 0; ks < 2; ++ks)
      bA[n][ks] = *(const f16x8*)(bW + (size_t)n * 32768 + ks * 512);
  SB;
  stageA(1, 1);
  asm volatile("s_waitcnt vmcnt(4)" ::: "memory");
  BAR;

#define MM16(AF, BC, KS, MOFF)                                                 \
  _Pragma("unroll") for (int m = 0; m < 4; ++m)                                \
    _Pragma("unroll") for (int n = 0; n < 4; ++n)                              \
      acc[m + MOFF][n] = __builtin_amdgcn_mfma_f32_16x16x32_f16(               \
          AF[m], BC[n][KS], acc[m + MOFF][n], 0, 0, 0);

#define TILE(T, BCUR, BNEXT, BUFI, BUFS)                                       \
  {                                                                            \
    if ((T) + 1 < NT) {                                                        \
      _Pragma("unroll") for (int n = 0; n < 4; ++n)                            \
        _Pragma("unroll") for (int ks = 0; ks < 2; ++ks)                       \
          BNEXT[n][ks] = *(const f16x8*)(bW + (size_t)n * 32768 +              \
                                         ((T) + 1) * 1024 + ks * 512);         \
    }                                                                          \
    SB;                                                                        \
    const char* bse = smem + (BUFI) * 32768;                                   \
    _Pragma("unroll") for (int m = 0; m < 4; ++m)                              \
      aL[m] = *(const f16x8*)(bse + abyteK[0] + m * 2048);                     \
    _Pragma("unroll") for (int m = 0; m < 4; ++m)                              \
      aH[m] = *(const f16x8*)(bse + abyteK[0] + (m + 4) * 2048);               \
    SB;                                                                        \
    if ((T) + 2 < NT) stageA((T) + 2, (BUFS));                                 \
    SB;                                                                        \
    LGKM(4); SB;                                                               \
    __builtin_amdgcn_s_setprio(1);                                             \
    MM16(aL, BCUR, 0, 0);                                                      \
    __builtin_amdgcn_s_setprio(0); SB;                                         \
    _Pragma("unroll") for (int m = 0; m < 4; ++m)                              \
      aL[m] = *(const f16x8*)(bse + abyteK[1] + m * 2048);                     \
    SB; LGKM(4); SB;                                                           \
    __builtin_amdgcn_s_setprio(1);                                             \
    MM16(aH, BCUR, 0, 4);                                                      \
    __builtin_amdgcn_s_setprio(0); SB;                                         \
    _Pragma("unroll") for (int m = 0; m < 4; ++m)                              \
      aH[m] = *(const f16x8*)(bse + abyteK[1] + (m + 4) * 2048);               \
    SB; LGKM(4); SB;                                                           \
    __builtin_amdgcn_s_setprio(1);                                             \
    MM16(aL, BCUR, 1, 0);                                                      \
    __builtin_amdgcn_s_setprio(0); SB;                                         \
    LGKM(0); SB;                                                               \
    __builtin_amdgcn_s_setprio(1);                                             \
    MM16(aH, BCUR, 1, 4);                                                      \
    __builtin_amdgcn_s_setprio(0); SB;                                         \
    if ((T) < NT - 1) {                                                        \
      if ((T) < NT - 2) asm volatile("s_waitcnt vmcnt(4)" ::: "memory");       \
      else              asm volatile("s_waitcnt vmcnt(0)" ::: "memory");       \
      BAR;                                                                     \
    }                                                                          \
  }

  int bi0 = 0, bi1 = 1, bi2 = 2;
  for (int t = 0; t < NT; t += 2) {
    TILE(t,     bA, bB, bi0, bi2);
    TILE(t + 1, bB, bA, bi1, bi0);
    const int n0_ = bi2, n1_ = bi0, n2_ = bi1;
    bi0 = n0_; bi1 = n1_; bi2 = n2_;
  }

  // ---- epilogue: a = relu(acc + b21); s = a @ W31; 2-pass LDS transpose-reduce ----
  float bb[4], w0v[4], w1v[4];
#pragma unroll
  for (int n = 0; n < 4; ++n) {
    int cg = n0 + wc * 64 + n * 16 + (lane & 15);
    bb[n]  = b21[cg];
    w0v[n] = w31[cg * 2 + 0];
    w1v[n] = w31[cg * 2 + 1];
  }
  float* red = (float*)smem;      // 64KB overlay per pass
#pragma unroll
  for (int p = 0; p < 2; ++p) {
    __syncthreads();
#pragma unroll
    for (int mq = 0; mq < 4; ++mq) {
      const int m = p * 4 + mq;
#pragma unroll
      for (int j = 0; j < 4; ++j) {
        float s0 = 0.f, s1 = 0.f;
#pragma unroll
        for (int n = 0; n < 4; ++n) {
          float a = fmaxf(acc[m][n][j] + bb[n], 0.f);
          s0 = fmaf(a, w0v[n], s0);
          s1 = fmaf(a, w1v[n], s1);
        }
        int rl = mq * 16 + (lane >> 4) * 4 + j;        // 0..63
        int idx = w * 2048 + rl * 32 + (lane & 15) * 2;
        red[idx]     = s0;
        red[idx + 1] = s1;
      }
    }
    __syncthreads();
    {
      const int w2 = tid >> 6, rl = tid & 63;
      const float* src = red + w2 * 2048 + rl * 32;
      float a0 = 0.f, a1 = 0.f;
#pragma unroll
      for (int k = 0; k < 8; ++k) {
        int kk = (k + (tid & 7)) & 7;
        float4 v = *(const float4*)(src + kk * 4);
        a0 += v.x + v.z;
        a1 += v.y + v.w;
      }
      int gr = r0 + (w2 >> 2) * 128 + p * 64 + rl;
      int strip = nblk * 4 + (w2 & 3);
      float2 o; o.x = a0; o.y = a1;
      *(float2*)(part + ((size_t)strip * M + gr) * 2) = o;
    }
  }
#undef SB
#undef BAR
#undef LGKM
#undef MM16
#undef TILE
}

// ---------- final: sum strips, add b31, QP clip, de/normalize ----------
__global__ __launch_bounds__(256)
void final_kernel(const float* __restrict__ part, const float* __restrict__ b31,
                  const float* __restrict__ om, const float* __restrict__ os,
                  const float* __restrict__ s0p, const float* __restrict__ s1p,
                  const float* __restrict__ s2p, const float* __restrict__ s3p,
                  float* __restrict__ out) {
  const int r = blockIdx.x * blockDim.x + threadIdx.x;
  float a0 = b31[0], a1 = b31[1];
#pragma unroll
  for (int s = 0; s < NSTRIP; ++s) {
    float2 v = *(const float2*)(part + ((size_t)s * M + r) * 2);
    a0 += v.x; a1 += v.y;
  }
  const float om0 = om[0], om1 = om[1], os0 = os[0], os1 = os[1];
  const float xa0 = a0 * os0 + om0;
  const float xa1 = a1 * os1 + om1;
  const float up0 = 1.0f + s2p[0];
  const float up1 = 1.0f + s0p[0];
  const float lo0 = -(1.0f + s3p[0]);
  const float lo1 = -(1.0f + s1p[0]);
  const float u0 = fminf(fmaxf(-xa0, lo0), up0);
  const float u1 = fminf(fmaxf(-xa1, lo1), up1);
  float2 o; o.x = (u0 - om0) / os0; o.y = (u1 - om1) / os1;
  *(float2*)(out + (size_t)r * 2) = o;
}

extern "C" void kernel_launch(void* const* d_in, const int* in_sizes, int n_in,
                              void* d_out, int out_size, void* d_ws, size_t ws_size,
                              hipStream_t stream) {
  const float* x    = (const float*)d_in[0];
  const float* W1   = (const float*)d_in[1];
  const float* b1   = (const float*)d_in[2];
  const float* W21  = (const float*)d_in[3];
  const float* b21  = (const float*)d_in[4];
  const float* W31  = (const float*)d_in[5];
  const float* b31  = (const float*)d_in[6];
  const float* omean = (const float*)d_in[13];
  const float* ostd  = (const float*)d_in[14];
  const float* s0 = (const float*)d_in[15];
  const float* s1 = (const float*)d_in[16];
  const float* s2 = (const float*)d_in[17];
  const float* s3 = (const float*)d_in[18];
  float* out = (float*)d_out;

  char* ws = (char*)d_ws;
  _Float16* hbuf = (_Float16*)(ws + WS_H);
  _Float16* w21b = (_Float16*)(ws + WS_W21B);
  float*    part = (float*)(ws + WS_PART);

  w21prep_kernel<<<dim3(32, 64), dim3(256), 0, stream>>>(W21, w21b);
  gemm1_kernel<<<dim3(512), dim3(256), 0, stream>>>(x, W1, b1, hbuf);
  gemm2_kernel<<<dim3((M / BM) * (N / BN)), dim3(512), 0, stream>>>(hbuf, w21b, b21, W31, part);
  final_kernel<<<dim3(M / 256), dim3(256), 0, stream>>>(part, b31, omean, ostd,
                                                        s0, s1, s2, s3, out);
}

// Round 8
// 155.625 us; speedup vs baseline: 1.8457x; 1.8457x over previous
//
#include <hip/hip_runtime.h>
#include <hip/hip_bf16.h>
#include <hip/hip_fp16.h>

#define DEVI __device__ __forceinline__

typedef _Float16 f16x8 __attribute__((ext_vector_type(8)));
typedef float f32x4 __attribute__((ext_vector_type(4)));

static constexpr int M = 32768;   // batch
static constexpr int N = 1024;    // H21
static constexpr int K = 2048;    // H1
static constexpr int BM = 256, BN = 256, BK = 64;
static constexpr int NT = K / BK;            // 32 k-tiles
static constexpr int NSTRIP = (N / BN) * 4;  // 16 partial strips

// ---- ws layout ----
static constexpr size_t WS_H    = 0;                       // f16 [M][K]
static constexpr size_t WS_W21T = 134217728;               // f16 [N][K]
static constexpr size_t WS_PART = 134217728 + 4194304;     // f32 [16][M][2]

using lds_vp = __attribute__((address_space(3))) void*;
using gbl_vp = const __attribute__((address_space(1))) void*;

DEVI void async_ld16(const void* g, void* l) {
  __builtin_amdgcn_global_load_lds((gbl_vp)(size_t)g,
                                   (lds_vp)(uint32_t)(size_t)l,
                                   16, 0, 0);
}

// ---------- prep: W21 [K][N] fp32 -> W21^T [N][K] f16 ----------
__global__ __launch_bounds__(256)
void w21cvt_kernel(const float* __restrict__ W21, _Float16* __restrict__ w21t) {
  __shared__ float sT[64][65];
  const int tid = threadIdx.x;
  const int k0 = blockIdx.x * 64;
  const int n0 = blockIdx.y * 64;
  const int row = tid >> 2;
#pragma unroll
  for (int q = 0; q < 4; ++q) {
    int c = (tid & 3) * 4 + q * 16;
    float4 v = *(const float4*)(W21 + (size_t)(k0 + row) * 1024 + n0 + c);
    sT[row][c + 0] = v.x; sT[row][c + 1] = v.y;
    sT[row][c + 2] = v.z; sT[row][c + 3] = v.w;
  }
  __syncthreads();
  const int n  = tid >> 2;
  const int kc = (tid & 3) * 16;
  union { _Float16 h[16]; float4 f4[2]; } u;
#pragma unroll
  for (int e = 0; e < 16; ++e) u.h[e] = (_Float16)sT[kc + e][n];
  float4* dst = (float4*)(w21t + (size_t)(n0 + n) * 2048 + k0 + kc);
  dst[0] = u.f4[0]; dst[1] = u.f4[1];
}

// ---------- gemm1: h = relu(x@W1 + b1), fp32 math, f16 out ----------
__global__ __launch_bounds__(256)
void gemm1_kernel(const float* __restrict__ x, const float* __restrict__ W1,
                  const float* __restrict__ b1, _Float16* __restrict__ hout) {
  __shared__ float sx[64 * 8];
  const int tid = threadIdx.x;
  const int r0 = blockIdx.x * 64;
  if (tid < 128) {
    *(float4*)&sx[tid * 4] = *(const float4*)(x + (size_t)r0 * 8 + tid * 4);
  }
  float w1r[8][8];
#pragma unroll
  for (int j = 0; j < 8; ++j) {
    *(float4*)&w1r[j][0] = *(const float4*)(W1 + j * 2048 + tid * 8);
    *(float4*)&w1r[j][4] = *(const float4*)(W1 + j * 2048 + tid * 8 + 4);
  }
  float bb[8];
  *(float4*)&bb[0] = *(const float4*)(b1 + tid * 8);
  *(float4*)&bb[4] = *(const float4*)(b1 + tid * 8 + 4);
  __syncthreads();
  for (int r = 0; r < 64; ++r) {
    float xv[8];
    *(float4*)&xv[0] = *(float4*)&sx[r * 8];
    *(float4*)&xv[4] = *(float4*)&sx[r * 8 + 4];
    float acc[8];
#pragma unroll
    for (int c = 0; c < 8; ++c) acc[c] = bb[c];
#pragma unroll
    for (int j = 0; j < 8; ++j)
#pragma unroll
      for (int c = 0; c < 8; ++c) acc[c] = fmaf(xv[j], w1r[j][c], acc[c]);
    union { f16x8 v; float4 f4; } u;
#pragma unroll
    for (int c = 0; c < 8; ++c) u.v[c] = (_Float16)fmaxf(acc[c], 0.f);
    *(float4*)(hout + (size_t)(r0 + r) * 2048 + tid * 8) = u.f4;
  }
}

// ---------- gemm2: 256x256, BK=64, 2 phases/tile (32 MFMA each), counted vmcnt ----------
// LDS per buffer (64 KiB): [A_s0 16K][A_s1 16K][B_s0 16K][B_s1 16K]; 2 buffers.
// Region layout: [256 rows][4 slots x 16B], slot = (chunk + (row>>1)) & 3.
__global__ __launch_bounds__(512, 2)
void gemm2_kernel(const _Float16* __restrict__ h, const _Float16* __restrict__ w21t,
                  const float* __restrict__ b21, const float* __restrict__ w31,
                  float* __restrict__ part) {
  __shared__ __align__(16) char smem[131072];

  const int tid  = threadIdx.x;
  const int lane = tid & 63;
  const int w    = tid >> 6;      // 0..7
  const int wr   = w >> 2;        // 0..1 -> 128 rows each
  const int wc   = w & 3;         // 0..3 -> 64 cols each

  // XCD-chunked bijective swizzle (512 % 8 == 0)
  const int lin  = blockIdx.x;
  const int swz  = (lin & 7) * 64 + (lin >> 3);
  const int nblk = swz & 3;
  const int mblk = swz >> 2;
  const int r0 = mblk * BM;
  const int n0 = nblk * BN;

  f32x4 acc[8][4] = {};

  // ---- staging (pre-swizzled global source, linear LDS dest) ----
  const int cA = ((tid & 3) - (tid >> 3)) & 3;
  const _Float16* pA = h    + (size_t)(r0 + (tid >> 2)) * K + cA * 8;
  const _Float16* pB = w21t + (size_t)(n0 + (tid >> 2)) * K + cA * 8;
  char* const lbase = smem + tid * 16;

  auto stageA = [&](int t, int hs) {
    const _Float16* g = pA + t * 64 + hs * 32;
    char* l = lbase + (t & 1) * 65536 + hs * 16384;
    async_ld16(g,                     l);
    async_ld16(g + (size_t)128 * K,   l + 8192);
  };
  auto stageB = [&](int t, int hs) {
    const _Float16* g = pB + t * 64 + hs * 32;
    char* l = lbase + (t & 1) * 65536 + 32768 + hs * 16384;
    async_ld16(g,                     l);
    async_ld16(g + (size_t)128 * K,   l + 8192);
  };

  // ---- ds_read addresses (swizzled; slot invariant under m/n offsets) ----
  const int arow0 = wr * 128 + (lane & 15);
  const int aslot = ((lane >> 4) + (arow0 >> 1)) & 3;
  const int abyte = arow0 * 64 + aslot * 16;            // + m*1024, + s*16384
  const int brow0 = wc * 64 + (lane & 15);
  const int bslot = ((lane >> 4) + (brow0 >> 1)) & 3;
  const int bbyte = 32768 + brow0 * 64 + bslot * 16;    // + n*1024, + s*16384

#define SB __builtin_amdgcn_sched_barrier(0)
#define BAR __builtin_amdgcn_s_barrier()
#define LGKM0 asm volatile("s_waitcnt lgkmcnt(0)" ::: "memory")

  // ---- prologue: stage tiles 0,1 (8 issues each) ----
  stageA(0, 0); stageB(0, 0); stageA(0, 1); stageB(0, 1);
  stageA(1, 0); stageB(1, 0); stageA(1, 1); stageB(1, 1);
  asm volatile("s_waitcnt vmcnt(8)" ::: "memory");   // tile 0 resident
  BAR;

  for (int t = 0; t < NT; ++t) {
    const char* base = smem + (t & 1) * 65536;
    f16x8 aF[8], bF[4];

    // ---- ph0: k-step 0 (regions s0) -> 32 MFMA ----
#pragma unroll
    for (int m = 0; m < 8; ++m) aF[m] = *(const f16x8*)(base + abyte + m * 1024);
#pragma unroll
    for (int n = 0; n < 4; ++n) bF[n] = *(const f16x8*)(base + bbyte + n * 1024);
    SB;
    BAR; LGKM0; SB;
    // stage s0 of tile t+2 into this buffer; reads of s0 above are complete
    // (issued pre-barrier, ~120cy; DMA lands >=300cy post-release)
    if (t + 2 < NT) { stageA(t + 2, 0); stageB(t + 2, 0); }
    SB;
    __builtin_amdgcn_s_setprio(1);
#pragma unroll
    for (int m = 0; m < 8; ++m)
#pragma unroll
      for (int n = 0; n < 4; ++n)
        acc[m][n] = __builtin_amdgcn_mfma_f32_16x16x32_f16(aF[m], bF[n], acc[m][n], 0, 0, 0);
    __builtin_amdgcn_s_setprio(0); SB;
    BAR;

    // ---- ph1: k-step 1 (regions s1) -> 32 MFMA ----
#pragma unroll
    for (int m = 0; m < 8; ++m) aF[m] = *(const f16x8*)(base + 16384 + abyte + m * 1024);
#pragma unroll
    for (int n = 0; n < 4; ++n) bF[n] = *(const f16x8*)(base + 16384 + bbyte + n * 1024);
    SB;
    BAR; LGKM0; SB;
    if (t + 2 < NT) { stageA(t + 2, 1); stageB(t + 2, 1); }
    SB;
    __builtin_amdgcn_s_setprio(1);
#pragma unroll
    for (int m = 0; m < 8; ++m)
#pragma unroll
      for (int n = 0; n < 4; ++n)
        acc[m][n] = __builtin_amdgcn_mfma_f32_16x16x32_f16(aF[m], bF[n], acc[m][n], 0, 0, 0);
    __builtin_amdgcn_s_setprio(0); SB;
    // retire tile t+1's 8 stages (issued during tile t-1); keeps t+2's 8 in flight
    if (t < NT - 2) asm volatile("s_waitcnt vmcnt(8)" ::: "memory");
    else            asm volatile("s_waitcnt vmcnt(0)" ::: "memory");
    BAR;
  }

  // ---- epilogue: a = relu(acc + b21); s = a @ W31; LDS transpose-reduce ----
  float bb[4], w0v[4], w1v[4];
#pragma unroll
  for (int n = 0; n < 4; ++n) {
    int cg = n0 + wc * 64 + n * 16 + (lane & 15);
    bb[n]  = b21[cg];
    w0v[n] = w31[cg * 2 + 0];
    w1v[n] = w31[cg * 2 + 1];
  }
  float* red = (float*)smem;
#pragma unroll
  for (int m = 0; m < 8; ++m) {
#pragma unroll
    for (int j = 0; j < 4; ++j) {
      float s0 = 0.f, s1 = 0.f;
#pragma unroll
      for (int n = 0; n < 4; ++n) {
        float a = fmaxf(acc[m][n][j] + bb[n], 0.f);
        s0 = fmaf(a, w0v[n], s0);
        s1 = fmaf(a, w1v[n], s1);
      }
      int row_local = m * 16 + (lane >> 4) * 4 + j;
      int idx = w * 4096 + row_local * 32 + (lane & 15) * 2;
      red[idx]     = s0;
      red[idx + 1] = s1;
    }
  }
  __syncthreads();
#pragma unroll
  for (int q = tid; q < 1024; q += 512) {
    const int w2 = q >> 7, rl = q & 127;
    const float* src = red + w2 * 4096 + rl * 32;
    float a0 = 0.f, a1 = 0.f;
#pragma unroll
    for (int k = 0; k < 8; ++k) {
      int kk = (k + (tid & 7)) & 7;
      float4 v = *(const float4*)(src + kk * 4);
      a0 += v.x + v.z;
      a1 += v.y + v.w;
    }
    int gr = r0 + (w2 >> 2) * 128 + rl;
    int strip = nblk * 4 + (w2 & 3);
    float2 o; o.x = a0; o.y = a1;
    *(float2*)(part + ((size_t)strip * M + gr) * 2) = o;
  }
#undef SB
#undef BAR
#undef LGKM0
}

// ---------- final: sum strips, add b31, QP clip, de/normalize ----------
__global__ __launch_bounds__(256)
void final_kernel(const float* __restrict__ part, const float* __restrict__ b31,
                  const float* __restrict__ om, const float* __restrict__ os,
                  const float* __restrict__ s0p, const float* __restrict__ s1p,
                  const float* __restrict__ s2p, const float* __restrict__ s3p,
                  float* __restrict__ out) {
  const int r = blockIdx.x * blockDim.x + threadIdx.x;
  float a0 = b31[0], a1 = b31[1];
#pragma unroll
  for (int s = 0; s < NSTRIP; ++s) {
    float2 v = *(const float2*)(part + ((size_t)s * M + r) * 2);
    a0 += v.x; a1 += v.y;
  }
  const float om0 = om[0], om1 = om[1], os0 = os[0], os1 = os[1];
  const float xa0 = a0 * os0 + om0;
  const float xa1 = a1 * os1 + om1;
  const float up0 = 1.0f + s2p[0];
  const float up1 = 1.0f + s0p[0];
  const float lo0 = -(1.0f + s3p[0]);
  const float lo1 = -(1.0f + s1p[0]);
  const float u0 = fminf(fmaxf(-xa0, lo0), up0);
  const float u1 = fminf(fmaxf(-xa1, lo1), up1);
  float2 o; o.x = (u0 - om0) / os0; o.y = (u1 - om1) / os1;
  *(float2*)(out + (size_t)r * 2) = o;
}

extern "C" void kernel_launch(void* const* d_in, const int* in_sizes, int n_in,
                              void* d_out, int out_size, void* d_ws, size_t ws_size,
                              hipStream_t stream) {
  const float* x    = (const float*)d_in[0];
  const float* W1   = (const float*)d_in[1];
  const float* b1   = (const float*)d_in[2];
  const float* W21  = (const float*)d_in[3];
  const float* b21  = (const float*)d_in[4];
  const float* W31  = (const float*)d_in[5];
  const float* b31  = (const float*)d_in[6];
  const float* omean = (const float*)d_in[13];
  const float* ostd  = (const float*)d_in[14];
  const float* s0 = (const float*)d_in[15];
  const float* s1 = (const float*)d_in[16];
  const float* s2 = (const float*)d_in[17];
  const float* s3 = (const float*)d_in[18];
  float* out = (float*)d_out;

  char* ws = (char*)d_ws;
  _Float16* hbuf = (_Float16*)(ws + WS_H);
  _Float16* w21t = (_Float16*)(ws + WS_W21T);
  float*    part = (float*)(ws + WS_PART);

  w21cvt_kernel<<<dim3(32, 16), dim3(256), 0, stream>>>(W21, w21t);
  gemm1_kernel<<<dim3(512), dim3(256), 0, stream>>>(x, W1, b1, hbuf);
  gemm2_kernel<<<dim3((M / BM) * (N / BN)), dim3(512), 0, stream>>>(hbuf, w21t, b21, W31, part);
  final_kernel<<<dim3(M / 256), dim3(256), 0, stream>>>(part, b31, omean, ostd,
                                                        s0, s1, s2, s3, out);
}

// Round 9
// 155.266 us; speedup vs baseline: 1.8499x; 1.0023x over previous
//
#include <hip/hip_runtime.h>
#include <hip/hip_bf16.h>
#include <hip/hip_fp16.h>

#define DEVI __device__ __forceinline__

typedef _Float16 f16x8 __attribute__((ext_vector_type(8)));
typedef float f32x4 __attribute__((ext_vector_type(4)));

static constexpr int M = 32768;   // batch
static constexpr int N = 1024;    // H21
static constexpr int K = 2048;    // H1
static constexpr int BM = 256, BN = 256, BK = 64;
static constexpr int NT = K / BK;            // 32 k-tiles
static constexpr int NSTRIP = (N / BN) * 4;  // 16 partial strips

// ---- ws layout ----
static constexpr size_t WS_H    = 0;                       // f16 [M][K]
static constexpr size_t WS_W21T = 134217728;               // f16 [N][K]
static constexpr size_t WS_PART = 134217728 + 4194304;     // f32 [16][M][2]

using lds_vp = __attribute__((address_space(3))) void*;
using gbl_vp = const __attribute__((address_space(1))) void*;

DEVI void async_ld16(const void* g, void* l) {
  __builtin_amdgcn_global_load_lds((gbl_vp)(size_t)g,
                                   (lds_vp)(uint32_t)(size_t)l,
                                   16, 0, 0);
}

// ---------- prep: W21 [K][N] fp32 -> W21^T [N][K] f16 ----------
__global__ __launch_bounds__(256)
void w21cvt_kernel(const float* __restrict__ W21, _Float16* __restrict__ w21t) {
  __shared__ float sT[64][65];
  const int tid = threadIdx.x;
  const int k0 = blockIdx.x * 64;
  const int n0 = blockIdx.y * 64;
  const int row = tid >> 2;
#pragma unroll
  for (int q = 0; q < 4; ++q) {
    int c = (tid & 3) * 4 + q * 16;
    float4 v = *(const float4*)(W21 + (size_t)(k0 + row) * 1024 + n0 + c);
    sT[row][c + 0] = v.x; sT[row][c + 1] = v.y;
    sT[row][c + 2] = v.z; sT[row][c + 3] = v.w;
  }
  __syncthreads();
  const int n  = tid >> 2;
  const int kc = (tid & 3) * 16;
  union { _Float16 h[16]; float4 f4[2]; } u;
#pragma unroll
  for (int e = 0; e < 16; ++e) u.h[e] = (_Float16)sT[kc + e][n];
  float4* dst = (float4*)(w21t + (size_t)(n0 + n) * 2048 + k0 + kc);
  dst[0] = u.f4[0]; dst[1] = u.f4[1];
}

// ---------- gemm1: h = relu(x@W1 + b1), fp32 math, f16 out ----------
__global__ __launch_bounds__(256)
void gemm1_kernel(const float* __restrict__ x, const float* __restrict__ W1,
                  const float* __restrict__ b1, _Float16* __restrict__ hout) {
  __shared__ float sx[64 * 8];
  const int tid = threadIdx.x;
  const int r0 = blockIdx.x * 64;
  if (tid < 128) {
    *(float4*)&sx[tid * 4] = *(const float4*)(x + (size_t)r0 * 8 + tid * 4);
  }
  float w1r[8][8];
#pragma unroll
  for (int j = 0; j < 8; ++j) {
    *(float4*)&w1r[j][0] = *(const float4*)(W1 + j * 2048 + tid * 8);
    *(float4*)&w1r[j][4] = *(const float4*)(W1 + j * 2048 + tid * 8 + 4);
  }
  float bb[8];
  *(float4*)&bb[0] = *(const float4*)(b1 + tid * 8);
  *(float4*)&bb[4] = *(const float4*)(b1 + tid * 8 + 4);
  __syncthreads();
  for (int r = 0; r < 64; ++r) {
    float xv[8];
    *(float4*)&xv[0] = *(float4*)&sx[r * 8];
    *(float4*)&xv[4] = *(float4*)&sx[r * 8 + 4];
    float acc[8];
#pragma unroll
    for (int c = 0; c < 8; ++c) acc[c] = bb[c];
#pragma unroll
    for (int j = 0; j < 8; ++j)
#pragma unroll
      for (int c = 0; c < 8; ++c) acc[c] = fmaf(xv[j], w1r[j][c], acc[c]);
    union { f16x8 v; float4 f4; } u;
#pragma unroll
    for (int c = 0; c < 8; ++c) u.v[c] = (_Float16)fmaxf(acc[c], 0.f);
    *(float4*)(hout + (size_t)(r0 + r) * 2048 + tid * 8) = u.f4;
  }
}

// ---------- gemm2: 256x256, BK=64, 1 barrier/tile, wave-drift overlap ----------
// LDS per buffer (64 KiB): [A_s0 16K][A_s1 16K][B_s0 16K][B_s1 16K]; 2 buffers.
// Region layout: [256 rows][4 slots x 16B], slot = (chunk + (row>>1)) & 3.
__global__ __launch_bounds__(512, 2)
void gemm2_kernel(const _Float16* __restrict__ h, const _Float16* __restrict__ w21t,
                  const float* __restrict__ b21, const float* __restrict__ w31,
                  float* __restrict__ part) {
  __shared__ __align__(16) char smem[131072];

  const int tid  = threadIdx.x;
  const int lane = tid & 63;
  const int w    = tid >> 6;      // 0..7
  const int wr   = w >> 2;        // 0..1 -> 128 rows each
  const int wc   = w & 3;         // 0..3 -> 64 cols each

  // XCD-chunked bijective swizzle (512 % 8 == 0)
  const int lin  = blockIdx.x;
  const int swz  = (lin & 7) * 64 + (lin >> 3);
  const int nblk = swz & 3;
  const int mblk = swz >> 2;
  const int r0 = mblk * BM;
  const int n0 = nblk * BN;

  f32x4 acc[8][4] = {};

  // ---- staging (pre-swizzled global source, linear LDS dest) ----
  const int cA = ((tid & 3) - (tid >> 3)) & 3;
  const _Float16* pA = h    + (size_t)(r0 + (tid >> 2)) * K + cA * 8;
  const _Float16* pB = w21t + (size_t)(n0 + (tid >> 2)) * K + cA * 8;
  char* const lbase = smem + tid * 16;

  auto stageA = [&](int t, int hs) {
    const _Float16* g = pA + t * 64 + hs * 32;
    char* l = lbase + (t & 1) * 65536 + hs * 16384;
    async_ld16(g,                     l);
    async_ld16(g + (size_t)128 * K,   l + 8192);
  };
  auto stageB = [&](int t, int hs) {
    const _Float16* g = pB + t * 64 + hs * 32;
    char* l = lbase + (t & 1) * 65536 + 32768 + hs * 16384;
    async_ld16(g,                     l);
    async_ld16(g + (size_t)128 * K,   l + 8192);
  };

  // ---- ds_read addresses (swizzled; slot invariant under m/n offsets) ----
  const int arow0 = wr * 128 + (lane & 15);
  const int aslot = ((lane >> 4) + (arow0 >> 1)) & 3;
  const int abyte = arow0 * 64 + aslot * 16;            // + m*1024, + s*16384
  const int brow0 = wc * 64 + (lane & 15);
  const int bslot = ((lane >> 4) + (brow0 >> 1)) & 3;
  const int bbyte = 32768 + brow0 * 64 + bslot * 16;    // + n*1024, + s*16384

#define SB __builtin_amdgcn_sched_barrier(0)
#define BAR __builtin_amdgcn_s_barrier()

  // ---- prologue: stage tile 0; drain; barrier ----
  stageA(0, 0); stageB(0, 0); stageA(0, 1); stageB(0, 1);
  asm volatile("s_waitcnt vmcnt(0)" ::: "memory");
  BAR;

  for (int t = 0; t < NT; ++t) {
    const char* base = smem + (t & 1) * 65536;

    // 1. prefetch tile t+1 into the other buffer (WAR-safe: its tile-(t-1)
    //    readers all retired their ds_reads before the last barrier)
    if (t + 1 < NT) { stageA(t + 1, 0); stageB(t + 1, 0);
                      stageA(t + 1, 1); stageB(t + 1, 1); }
    SB;

    // 2. issue ALL 24 ds_reads (s0 first, then s1) — in-order DS retirement
    f16x8 aF0[8], bF0[4], aF1[8], bF1[4];
#pragma unroll
    for (int m = 0; m < 8; ++m) aF0[m] = *(const f16x8*)(base + abyte + m * 1024);
#pragma unroll
    for (int n = 0; n < 4; ++n) bF0[n] = *(const f16x8*)(base + bbyte + n * 1024);
#pragma unroll
    for (int m = 0; m < 8; ++m) aF1[m] = *(const f16x8*)(base + 16384 + abyte + m * 1024);
#pragma unroll
    for (int n = 0; n < 4; ++n) bF1[n] = *(const f16x8*)(base + 16384 + bbyte + n * 1024);
    SB;

    // 3. wait first 12 (s0 set) -> MFMA s0; s1 reads still in flight
    asm volatile("s_waitcnt lgkmcnt(12)" ::: "memory");
    SB;
    __builtin_amdgcn_s_setprio(1);
#pragma unroll
    for (int m = 0; m < 8; ++m)
#pragma unroll
      for (int n = 0; n < 4; ++n)
        acc[m][n] = __builtin_amdgcn_mfma_f32_16x16x32_f16(aF0[m], bF0[n], acc[m][n], 0, 0, 0);
    __builtin_amdgcn_s_setprio(0); SB;

    // 4. wait remaining -> MFMA s1
    asm volatile("s_waitcnt lgkmcnt(0)" ::: "memory");
    SB;
    __builtin_amdgcn_s_setprio(1);
#pragma unroll
    for (int m = 0; m < 8; ++m)
#pragma unroll
      for (int n = 0; n < 4; ++n)
        acc[m][n] = __builtin_amdgcn_mfma_f32_16x16x32_f16(aF1[m], bF1[n], acc[m][n], 0, 0, 0);
    __builtin_amdgcn_s_setprio(0); SB;

    // 5. tile t+1 data landed; single barrier per tile
    asm volatile("s_waitcnt vmcnt(0)" ::: "memory");
    BAR;
  }

  // ---- epilogue: a = relu(acc + b21); s = a @ W31; LDS transpose-reduce ----
  float bb[4], w0v[4], w1v[4];
#pragma unroll
  for (int n = 0; n < 4; ++n) {
    int cg = n0 + wc * 64 + n * 16 + (lane & 15);
    bb[n]  = b21[cg];
    w0v[n] = w31[cg * 2 + 0];
    w1v[n] = w31[cg * 2 + 1];
  }
  float* red = (float*)smem;
#pragma unroll
  for (int m = 0; m < 8; ++m) {
#pragma unroll
    for (int j = 0; j < 4; ++j) {
      float s0 = 0.f, s1 = 0.f;
#pragma unroll
      for (int n = 0; n < 4; ++n) {
        float a = fmaxf(acc[m][n][j] + bb[n], 0.f);
        s0 = fmaf(a, w0v[n], s0);
        s1 = fmaf(a, w1v[n], s1);
      }
      int row_local = m * 16 + (lane >> 4) * 4 + j;
      int idx = w * 4096 + row_local * 32 + (lane & 15) * 2;
      red[idx]     = s0;
      red[idx + 1] = s1;
    }
  }
  __syncthreads();
#pragma unroll
  for (int q = tid; q < 1024; q += 512) {
    const int w2 = q >> 7, rl = q & 127;
    const float* src = red + w2 * 4096 + rl * 32;
    float a0 = 0.f, a1 = 0.f;
#pragma unroll
    for (int k = 0; k < 8; ++k) {
      int kk = (k + (tid & 7)) & 7;
      float4 v = *(const float4*)(src + kk * 4);
      a0 += v.x + v.z;
      a1 += v.y + v.w;
    }
    int gr = r0 + (w2 >> 2) * 128 + rl;
    int strip = nblk * 4 + (w2 & 3);
    float2 o; o.x = a0; o.y = a1;
    *(float2*)(part + ((size_t)strip * M + gr) * 2) = o;
  }
#undef SB
#undef BAR
}

// ---------- final: sum strips, add b31, QP clip, de/normalize ----------
__global__ __launch_bounds__(256)
void final_kernel(const float* __restrict__ part, const float* __restrict__ b31,
                  const float* __restrict__ om, const float* __restrict__ os,
                  const float* __restrict__ s0p, const float* __restrict__ s1p,
                  const float* __restrict__ s2p, const float* __restrict__ s3p,
                  float* __restrict__ out) {
  const int r = blockIdx.x * blockDim.x + threadIdx.x;
  float a0 = b31[0], a1 = b31[1];
#pragma unroll
  for (int s = 0; s < NSTRIP; ++s) {
    float2 v = *(const float2*)(part + ((size_t)s * M + r) * 2);
    a0 += v.x; a1 += v.y;
  }
  const float om0 = om[0], om1 = om[1], os0 = os[0], os1 = os[1];
  const float xa0 = a0 * os0 + om0;
  const float xa1 = a1 * os1 + om1;
  const float up0 = 1.0f + s2p[0];
  const float up1 = 1.0f + s0p[0];
  const float lo0 = -(1.0f + s3p[0]);
  const float lo1 = -(1.0f + s1p[0]);
  const float u0 = fminf(fmaxf(-xa0, lo0), up0);
  const float u1 = fminf(fmaxf(-xa1, lo1), up1);
  float2 o; o.x = (u0 - om0) / os0; o.y = (u1 - om1) / os1;
  *(float2*)(out + (size_t)r * 2) = o;
}

extern "C" void kernel_launch(void* const* d_in, const int* in_sizes, int n_in,
                              void* d_out, int out_size, void* d_ws, size_t ws_size,
                              hipStream_t stream) {
  const float* x    = (const float*)d_in[0];
  const float* W1   = (const float*)d_in[1];
  const float* b1   = (const float*)d_in[2];
  const float* W21  = (const float*)d_in[3];
  const float* b21  = (const float*)d_in[4];
  const float* W31  = (const float*)d_in[5];
  const float* b31  = (const float*)d_in[6];
  const float* omean = (const float*)d_in[13];
  const float* ostd  = (const float*)d_in[14];
  const float* s0 = (const float*)d_in[15];
  const float* s1 = (const float*)d_in[16];
  const float* s2 = (const float*)d_in[17];
  const float* s3 = (const float*)d_in[18];
  float* out = (float*)d_out;

  char* ws = (char*)d_ws;
  _Float16* hbuf = (_Float16*)(ws + WS_H);
  _Float16* w21t = (_Float16*)(ws + WS_W21T);
  float*    part = (float*)(ws + WS_PART);

  w21cvt_kernel<<<dim3(32, 16), dim3(256), 0, stream>>>(W21, w21t);
  gemm1_kernel<<<dim3(512), dim3(256), 0, stream>>>(x, W1, b1, hbuf);
  gemm2_kernel<<<dim3((M / BM) * (N / BN)), dim3(512), 0, stream>>>(hbuf, w21t, b21, W31, part);
  final_kernel<<<dim3(M / 256), dim3(256), 0, stream>>>(part, b31, omean, ostd,
                                                        s0, s1, s2, s3, out);
}